// Round 9
// baseline (110.152 us; speedup 1.0000x reference)
//
#include <hip/hip_runtime.h>
#include <cstdint>

// ECT loss, exact elementwise formulation (absmax 0.0 preserved).
// A[bc][r][d] = sum_p dw[b,p,c] * sigmoid(8*(lin_r - <x_p, v_d>)), c in {0,1};
// c2 = -(c0+c1); loss = mean over 12288.
//
// R9: double waves/SIMD at IDENTICAL total instruction count (r-split).
//  * R8 calibration: body = ~52 VALU x 2cy + 4 trans; busy ~34us, wall 52us
//    -> 30-35% issue-idle at 4 waves/SIMD. Last un-exonerated suspect:
//    per-wave dependency chains (z->pz->rcp->s->fma) with too few resident
//    waves to cover the bubbles.
//  * 1024 blocks x 512 threads: thread (d=t&31, rg=t>>5 in [0,16)) owns 4
//    r-values (was 8). No cross-thread reduction (unlike R1's voxel-split):
//    each thread owns complete output rows, stores directly. Same absolute
//    (even,odd) rcp pairs -> bit-identical sigmoids and accumulation order.
//  * VGPR 32, LDS 16KB -> 4 blocks/CU x 8 waves = 8 waves/SIMD (2x R8).
//    launch_bounds(512,8) pins VGPR below the 64-reg occupancy cliff.
//  * Etab + folded memset + store path + red kept from R8 (proven).
// Fallback chain by ws_size: 1024-r-split -> 512-store -> atomic (proven).

#define P_TOT 110592
#define NREP 4  // atomic fallback only

__device__ __forceinline__ uint32_t rotl32(uint32_t x, int d) {
  return (x << d) | (x >> (32 - d));
}

// threefry2x32, key = (0,17) — bit-exact vs jax (verified)
__device__ __forceinline__ void threefry_0_17(uint32_t x0, uint32_t x1,
                                              uint32_t& o0, uint32_t& o1) {
  const uint32_t ks0 = 0u, ks1 = 17u, ks2 = 0x1BD11BDAu ^ 0u ^ 17u;
  x0 += ks0; x1 += ks1;
#define R4(a,b,c,dd) \
  x0 += x1; x1 = rotl32(x1,(a)); x1 ^= x0; \
  x0 += x1; x1 = rotl32(x1,(b)); x1 ^= x0; \
  x0 += x1; x1 = rotl32(x1,(c)); x1 ^= x0; \
  x0 += x1; x1 = rotl32(x1,(dd)); x1 ^= x0;
  R4(13,15,26,6)   x0 += ks1; x1 += ks2 + 1u;
  R4(17,29,16,24)  x0 += ks2; x1 += ks0 + 2u;
  R4(13,15,26,6)   x0 += ks0; x1 += ks1 + 3u;
  R4(17,29,16,24)  x0 += ks1; x1 += ks2 + 4u;
  R4(13,15,26,6)   x0 += ks2; x1 += ks0 + 5u;
#undef R4
  o0 = x0; o1 = x1;
}

// XLA ErfInv32 — bit-exact vs jax (verified)
__device__ __forceinline__ float erfinv_f32(float x) {
  float w = -log1pf(-x * x);
  float p;
  if (w < 5.0f) {
    w = w - 2.5f;
    p = 2.81022636e-08f;
    p = fmaf(p, w, 3.43273939e-07f);
    p = fmaf(p, w, -3.5233877e-06f);
    p = fmaf(p, w, -4.39150654e-06f);
    p = fmaf(p, w, 0.00021858087f);
    p = fmaf(p, w, -0.00125372503f);
    p = fmaf(p, w, -0.00417768164f);
    p = fmaf(p, w, 0.246640727f);
    p = fmaf(p, w, 1.50140941f);
  } else {
    w = sqrtf(w) - 3.0f;
    p = -0.000200214257f;
    p = fmaf(p, w, 0.000100950558f);
    p = fmaf(p, w, 0.00134934322f);
    p = fmaf(p, w, 0.000337081863f);
    p = fmaf(p, w, 0.00573950773f);
    p = fmaf(p, w, -0.0076224613f);
    p = fmaf(p, w, 0.00943887047f);
    p = fmaf(p, w, 1.00167406f);
    p = fmaf(p, w, 2.83297682f);
  }
  return p * x;
}

// ---------- common prologue: dirs + voxdw + Etab (NT = block threads) ----------
template <int VOXN, int NT>
__device__ __forceinline__ void ect_prologue(
    const float* __restrict__ pred, const int* __restrict__ tgt,
    float* dirs, float4* voxdw, float* Etab, int t, int bx) {
  const int cbase = bx * VOXN;
  if (t < 96) {
    uint32_t o0, o1;
    threefry_0_17(0u, (uint32_t)t, o0, o1);
    uint32_t bits = o0 ^ o1;
    float u = __uint_as_float((bits >> 9) | 0x3F800000u) - 1.0f;
    const float lo = -0.99999994f;
    float v = fmaf(u, 2.0f, lo);
    v = fmaxf(v, lo);
    dirs[t] = 1.41421356237f * erfinv_f32(v);
  }
  __syncthreads();
  if (t < 32) {
    float a = dirs[t], b = dirs[32 + t], c = dirs[64 + t];
    float n = fmaxf(sqrtf(a * a + b * b + c * c), 1e-12f);
    dirs[t] = a / n; dirs[32 + t] = b / n; dirs[64 + t] = c / n;
  }
  if (t < VOXN) {   // voxdw: independent of dirs, overlaps normalize
    int p = cbase + t;
    float w[4];
#pragma unroll
    for (int b = 0; b < 2; b++) {
      const float* pb = pred + b * (3 * P_TOT) + p;
      float x0 = pb[0], x1 = pb[P_TOT], x2 = pb[2 * P_TOT];
      float m = fmaxf(x0, fmaxf(x1, x2));
      float e0 = __expf(x0 - m), e1 = __expf(x1 - m), e2 = __expf(x2 - m);
      float inv = 1.0f / (e0 + e1 + e2);
      int tg = tgt[b * P_TOT + p];
      w[b * 2 + 0] = e0 * inv - ((tg == 0) ? 1.0f : 0.0f);
      w[b * 2 + 1] = e1 * inv - ((tg == 1) ? 1.0f : 0.0f);
    }
    voxdw[t] = float4{w[0], w[1], w[2], w[3]};
  }
  __syncthreads();
  // Etab fill: identical nh/exp expression as the original in-loop code.
  const float delta = 2.0f / 47.0f;
  for (int i = t; i < VOXN * 32; i += NT) {
    int v = i >> 5, dd = i & 31;
    int p = cbase + v;
    int ix = p / 2304; int rem = p - ix * 2304;
    int iy = rem / 48; int iz = rem - iy * 48;
    float cx = (float)ix * delta - 1.0f;
    float cy = (float)iy * delta - 1.0f;
    float cz = (float)iz * delta - 1.0f;
    float nh = fmaf(cz, dirs[64 + dd], fmaf(cy, dirs[32 + dd], cx * dirs[dd]));
    Etab[i] = __expf(8.0f * nh);        // <= e^13.9, no overflow
  }
  __syncthreads();
}

// ---------- primary: 512-thread r-split main ----------
template <int VOXN>
__global__ __launch_bounds__(512, 8) void ect_main_5(
    const float* __restrict__ pred, const int* __restrict__ tgt,
    float* __restrict__ part, float* __restrict__ gacc2) {
  __shared__ float dirs[96];
  __shared__ float4 voxdw[VOXN];
  __shared__ float Etab[VOXN * 32];
  const int t = threadIdx.x;
  const int bx = blockIdx.x;
  const int d = t & 31;
  const int rg = t >> 5;          // 0..15; thread owns r = rg*4 + j, j<4

  // folded memset: blocks 0..3 zero gacc2 (8192 floats), block 4 the ticket.
  if (bx < 4) ((float4*)gacc2)[bx * 512 + t] = float4{0.f, 0.f, 0.f, 0.f};
  if (bx == 4 && t == 0) *(unsigned int*)(gacc2 + 8192) = 0u;

  ect_prologue<VOXN, 512>(pred, tgt, dirs, voxdw, Etab, t, bx);

  const float radius = 1.1f * 1.7320508075688772f;
  const float step = (2.0f * radius) / 63.0f;
  float K[4];
#pragma unroll
  for (int j = 0; j < 4; j++) {
    float lin = fmaf((float)(rg * 4 + j), step, -radius);
    K[j] = __expf(-8.0f * lin);
  }
  float acc[4][4];
#pragma unroll
  for (int j = 0; j < 4; j++)
#pragma unroll
    for (int bc = 0; bc < 4; bc++) acc[j][bc] = 0.0f;

  // main loop: same absolute (even,odd) rcp pairs as the 256-thr version
  // -> bit-identical sigmoids; half the chain depth, 2x resident waves.
#pragma unroll 4
  for (int v = 0; v < VOXN; v++) {
    float4 w = voxdw[v];
    float E = Etab[(v << 5) + d];         // broadcast ds_read_b32
    float z[4];
#pragma unroll
    for (int j = 0; j < 4; j++) z[j] = fmaf(E, K[j], 1.0f);  // 1..4.4e12
#pragma unroll
    for (int h = 0; h < 2; h++) {
      // paired reciprocal: product <= 2e25, no overflow
      float pz = z[2 * h] * z[2 * h + 1];
      float rr = __builtin_amdgcn_rcpf(pz);
      float s0 = z[2 * h + 1] * rr;       // sigmoid for r = rg*4+2h
      float s1 = z[2 * h] * rr;           // sigmoid for r = rg*4+2h+1
      acc[2 * h][0] = fmaf(w.x, s0, acc[2 * h][0]);
      acc[2 * h][1] = fmaf(w.y, s0, acc[2 * h][1]);
      acc[2 * h][2] = fmaf(w.z, s0, acc[2 * h][2]);
      acc[2 * h][3] = fmaf(w.w, s0, acc[2 * h][3]);
      acc[2 * h + 1][0] = fmaf(w.x, s1, acc[2 * h + 1][0]);
      acc[2 * h + 1][1] = fmaf(w.y, s1, acc[2 * h + 1][1]);
      acc[2 * h + 1][2] = fmaf(w.z, s1, acc[2 * h + 1][2]);
      acc[2 * h + 1][3] = fmaf(w.w, s1, acc[2 * h + 1][3]);
    }
  }

  // epilogue: coalesced stores; thread owns rows r = rg*4+j entirely
  float4* prt = (float4*)part + (size_t)bx * 2048;
#pragma unroll
  for (int j = 0; j < 4; j++) {
    prt[(rg * 4 + j) * 32 + d] =
        float4{acc[j][0], acc[j][1], acc[j][2], acc[j][3]};
  }
}

__global__ __launch_bounds__(256) void ect_red(
    const float* __restrict__ part, float* __restrict__ gacc2,
    float* __restrict__ out, int ngrid) {
  __shared__ float redf[4];
  __shared__ int islast;
  const int t = threadIdx.x;
  const int rc = blockIdx.x >> 3;       // slice chunk (32 slices each)
  const int cc = blockIdx.x & 7;        // column chunk (256 float4)
  const int c4 = cc * 256 + t;          // float4 column in [0, 2048)
  const float4* p4 = (const float4*)part;

  float a0 = 0.f, a1 = 0.f, a2 = 0.f, a3 = 0.f;
#pragma unroll 8
  for (int r = rc * 32; r < rc * 32 + 32; ++r) {
    float4 v = p4[(size_t)r * 2048 + c4];   // 1KB-coalesced per wave per r
    a0 += v.x; a1 += v.y; a2 += v.z; a3 += v.w;
  }
  atomicAdd(&gacc2[c4 * 4 + 0], a0);
  atomicAdd(&gacc2[c4 * 4 + 1], a1);
  atomicAdd(&gacc2[c4 * 4 + 2], a2);
  atomicAdd(&gacc2[c4 * 4 + 3], a3);

  __syncthreads();                       // drains vmcnt(0) per wave
  unsigned int* cnt = (unsigned int*)(gacc2 + 8192);
  if (t == 0) {
    unsigned int old = __hip_atomic_fetch_add(cnt, 1u, __ATOMIC_RELAXED,
                                              __HIP_MEMORY_SCOPE_AGENT);
    islast = (old == (unsigned int)(ngrid - 1)) ? 1 : 0;
  }
  __syncthreads();
  if (islast) {
    float s = 0.0f;
    for (int i = t; i < 2048; i += 256) {  // i = r*32 + d
      const unsigned long long* p64 =
          (const unsigned long long*)(gacc2 + i * 4);
      unsigned long long q0 = __hip_atomic_load(p64, __ATOMIC_RELAXED,
                                                __HIP_MEMORY_SCOPE_AGENT);
      unsigned long long q1 = __hip_atomic_load(p64 + 1, __ATOMIC_RELAXED,
                                                __HIP_MEMORY_SCOPE_AGENT);
      float b0 = __uint_as_float((unsigned int)q0);
      float b1 = __uint_as_float((unsigned int)(q0 >> 32));
      float b2 = __uint_as_float((unsigned int)q1);
      float b3 = __uint_as_float((unsigned int)(q1 >> 32));
      s += b0 * b0 + b1 * b1 + (b0 + b1) * (b0 + b1)
         + b2 * b2 + b3 * b3 + (b2 + b3) * (b2 + b3);
    }
#pragma unroll
    for (int off = 32; off > 0; off >>= 1) s += __shfl_down(s, off, 64);
    if ((t & 63) == 0) redf[t >> 6] = s;
    __syncthreads();
    if (t == 0)
      out[0] = (redf[0] + redf[1] + redf[2] + redf[3]) * (1.0f / 12288.0f);
  }
}

// ---------- 256-thread compute (fallback paths, proven R8 code) ----------
template <int VOXN>
__device__ __forceinline__ void ect_block_compute(
    const float* __restrict__ pred, const int* __restrict__ tgt,
    float* dirs, float4* voxdw, float* Etab,
    int t, int bx, float acc[8][4]) {
  const int d = t & 31;
  const int rg = t >> 5;
  ect_prologue<VOXN, 256>(pred, tgt, dirs, voxdw, Etab, t, bx);

  const float radius = 1.1f * 1.7320508075688772f;
  const float step = (2.0f * radius) / 63.0f;
  float K[8];
#pragma unroll
  for (int j = 0; j < 8; j++) {
    float lin = fmaf((float)(rg * 8 + j), step, -radius);
    K[j] = __expf(-8.0f * lin);
  }
#pragma unroll
  for (int j = 0; j < 8; j++)
#pragma unroll
    for (int bc = 0; bc < 4; bc++) acc[j][bc] = 0.0f;

#pragma unroll 4
  for (int v = 0; v < VOXN; v++) {
    float4 w = voxdw[v];
    float E = Etab[(v << 5) + d];
    float z[8];
#pragma unroll
    for (int j = 0; j < 8; j++) z[j] = fmaf(E, K[j], 1.0f);
#pragma unroll
    for (int h = 0; h < 4; h++) {
      float pz = z[2 * h] * z[2 * h + 1];
      float rr = __builtin_amdgcn_rcpf(pz);
      float s0 = z[2 * h + 1] * rr;
      float s1 = z[2 * h] * rr;
      acc[2 * h][0] = fmaf(w.x, s0, acc[2 * h][0]);
      acc[2 * h][1] = fmaf(w.y, s0, acc[2 * h][1]);
      acc[2 * h][2] = fmaf(w.z, s0, acc[2 * h][2]);
      acc[2 * h][3] = fmaf(w.w, s0, acc[2 * h][3]);
      acc[2 * h + 1][0] = fmaf(w.x, s1, acc[2 * h + 1][0]);
      acc[2 * h + 1][1] = fmaf(w.y, s1, acc[2 * h + 1][1]);
      acc[2 * h + 1][2] = fmaf(w.z, s1, acc[2 * h + 1][2]);
      acc[2 * h + 1][3] = fmaf(w.w, s1, acc[2 * h + 1][3]);
    }
  }
}

template <int VOXN>
__global__ __launch_bounds__(256, 2) void ect_main_st(
    const float* __restrict__ pred, const int* __restrict__ tgt,
    float* __restrict__ part, float* __restrict__ gacc2) {
  __shared__ float dirs[96];
  __shared__ float4 voxdw[VOXN];
  __shared__ float Etab[VOXN * 32];
  const int t = threadIdx.x;
  const int bx = blockIdx.x;
  const int d = t & 31;
  const int rg = t >> 5;
  if (bx < 8) ((float4*)gacc2)[bx * 256 + t] = float4{0.f, 0.f, 0.f, 0.f};
  if (bx == 8 && t == 0) *(unsigned int*)(gacc2 + 8192) = 0u;
  float acc[8][4];
  ect_block_compute<VOXN>(pred, tgt, dirs, voxdw, Etab, t, bx, acc);
  float4* prt = (float4*)part + (size_t)bx * 2048;
#pragma unroll
  for (int j = 0; j < 8; j++) {
    prt[(rg * 8 + j) * 32 + d] =
        float4{acc[j][0], acc[j][1], acc[j][2], acc[j][3]};
  }
}

// ---------- atomic fallback (proven structure) ----------
__global__ __launch_bounds__(256, 2) void ect_main_at(
    const float* __restrict__ pred, const int* __restrict__ tgt,
    float* __restrict__ gacc) {
  __shared__ float dirs[96];
  __shared__ float4 voxdw[216];
  __shared__ float Etab[216 * 32];
  const int t = threadIdx.x;
  const int bx = blockIdx.x;
  const int d = t & 31;
  const int rg = t >> 5;
  float acc[8][4];
  ect_block_compute<216>(pred, tgt, dirs, voxdw, Etab, t, bx, acc);
  float* grep = gacc + (size_t)(bx & (NREP - 1)) * 8192;
#pragma unroll
  for (int j = 0; j < 8; j++) {
    int base = ((rg * 8 + j) * 32 + d) * 4;
    atomicAdd(&grep[base + 0], acc[j][0]);
    atomicAdd(&grep[base + 1], acc[j][1]);
    atomicAdd(&grep[base + 2], acc[j][2]);
    atomicAdd(&grep[base + 3], acc[j][3]);
  }
}

__global__ __launch_bounds__(256) void ect_fin(
    const float* __restrict__ gacc, float* __restrict__ out) {
  __shared__ float red[4];
  int t = threadIdx.x;
  float s = 0.0f;
  for (int i = t; i < 2048; i += 256) {
    float a0 = 0.f, a1 = 0.f, a2 = 0.f, a3 = 0.f;
#pragma unroll
    for (int rep = 0; rep < NREP; rep++) {
      const float4 g = *(const float4*)(gacc + (size_t)rep * 8192 + i * 4);
      a0 += g.x; a1 += g.y; a2 += g.z; a3 += g.w;
    }
    s += a0 * a0 + a1 * a1 + (a0 + a1) * (a0 + a1)
       + a2 * a2 + a3 * a3 + (a2 + a3) * (a2 + a3);
  }
#pragma unroll
  for (int off = 32; off > 0; off >>= 1) s += __shfl_down(s, off, 64);
  if ((t & 63) == 0) red[t >> 6] = s;
  __syncthreads();
  if (t == 0) out[0] = (red[0] + red[1] + red[2] + red[3]) * (1.0f / 12288.0f);
}

extern "C" void kernel_launch(void* const* d_in, const int* in_sizes, int n_in,
                              void* d_out, int out_size, void* d_ws, size_t ws_size,
                              hipStream_t stream) {
  const float* pred = (const float*)d_in[0];
  const int* tgt = (const int*)d_in[1];
  float* ws = (float*)d_ws;
  float* out = (float*)d_out;

  const size_t need1024 = ((size_t)1024 * 8192 + 8192 + 64) * sizeof(float);
  const size_t need512 = ((size_t)512 * 8192 + 8192 + 64) * sizeof(float);

  if (ws_size >= need1024) {
    // 1024 blocks x 512 threads x 108 voxels (r-split, 8 waves/SIMD)
    float* part = ws;                                   // [1024][8192]
    float* gacc2 = ws + (size_t)1024 * 8192;
    hipLaunchKernelGGL(ect_main_5<108>, dim3(1024), dim3(512), 0, stream,
                       pred, tgt, part, gacc2);
    hipLaunchKernelGGL(ect_red, dim3(256), dim3(256), 0, stream,
                       part, gacc2, out, 256);
  } else if (ws_size >= need512) {
    float* part = ws;                                   // [512][8192]
    float* gacc2 = ws + (size_t)512 * 8192;
    hipLaunchKernelGGL(ect_main_st<216>, dim3(512), dim3(256), 0, stream,
                       pred, tgt, part, gacc2);
    hipLaunchKernelGGL(ect_red, dim3(128), dim3(256), 0, stream,
                       part, gacc2, out, 128);
  } else {
    float* gacc = ws;                                   // 4*8192 floats
    hipMemsetAsync(gacc, 0, (size_t)NREP * 8192 * sizeof(float), stream);
    hipLaunchKernelGGL(ect_main_at, dim3(512), dim3(256), 0, stream,
                       pred, tgt, gacc);
    hipLaunchKernelGGL(ect_fin, dim3(1), dim3(256), 0, stream, gacc, out);
  }
}